// Round 8
// baseline (496.506 us; speedup 1.0000x reference)
//
#include <hip/hip_runtime.h>
#include <hip/hip_cooperative_groups.h>
#include <hip/hip_bf16.h>

namespace cg = cooperative_groups;

#define NTOK 2048
#define DIM  1024
#define DEXP 512
#define NEXP 8
#define DSH  1024          // shared expert width
#define KH   5120          // DSH + NEXP*DEXP
#define MAXROWS 5120       // compacted routed slots upper bound

typedef __hip_bfloat16 bf16;
typedef __attribute__((ext_vector_type(8))) short bf16x8;
typedef __attribute__((ext_vector_type(4))) float floatx4;

// async global->LDS, 16B/lane. LDS dest = wave-uniform base + lane*16 (HW adds).
__device__ __forceinline__ void gl_lds16(const bf16* g, bf16* l) {
    __builtin_amdgcn_global_load_lds(
        (const __attribute__((address_space(1))) void*)g,
        (__attribute__((address_space(3))) void*)l, 16, 0, 0);
}

__device__ __forceinline__ float b2f(short s) {
    union { float f; unsigned u; } v;
    v.u = ((unsigned)(unsigned short)s) << 16;
    return v.f;
}

struct B4 { bf16 a, b, c, d; };   // 8-byte bf16 quad

// ===========================================================================
// Phase bodies as __device__ functions — shared by the cooperative kernel and
// the multi-launch fallback, so both paths compute identical results.
// ===========================================================================

// ---- gating (+x->bf16 cast) for gate-block gb in [0,512): 4 tokens, 1/wave --
__device__ __forceinline__ void ph_gate(int gb, const float* __restrict__ x,
                                        const float* __restrict__ Wg,
                                        bf16* __restrict__ Xb,
                                        int2* __restrict__ te, float2* __restrict__ tp) {
    const int wave = threadIdx.x >> 6, lane = threadIdx.x & 63;
    int tok = gb * 4 + wave;
    const float* xr = x + (long)tok * DIM;
    bf16* xo = Xb + (long)tok * DIM;
    float acc[NEXP] = {0.f, 0.f, 0.f, 0.f, 0.f, 0.f, 0.f, 0.f};
#pragma unroll
    for (int i = 0; i < 4; i++) {
        int d = lane * 4 + i * 256;
        float4 xv = *(const float4*)(xr + d);
        B4 o{__float2bfloat16(xv.x), __float2bfloat16(xv.y),
             __float2bfloat16(xv.z), __float2bfloat16(xv.w)};
        *(B4*)(xo + d) = o;
#pragma unroll
        for (int j = 0; j < 4; j++) {
            float xs = (j == 0) ? xv.x : (j == 1) ? xv.y : (j == 2) ? xv.z : xv.w;
            float4 w0 = *(const float4*)(Wg + (d + j) * NEXP);
            float4 w1 = *(const float4*)(Wg + (d + j) * NEXP + 4);
            acc[0] += xs * w0.x; acc[1] += xs * w0.y; acc[2] += xs * w0.z; acc[3] += xs * w0.w;
            acc[4] += xs * w1.x; acc[5] += xs * w1.y; acc[6] += xs * w1.z; acc[7] += xs * w1.w;
        }
    }
#pragma unroll
    for (int e = 0; e < NEXP; e++)
#pragma unroll
        for (int off = 32; off; off >>= 1)
            acc[e] += __shfl_xor(acc[e], off);
    if (lane == 0) {
        float m = acc[0];
#pragma unroll
        for (int e = 1; e < NEXP; e++) m = fmaxf(m, acc[e]);
        float p[NEXP], s = 0.f;
#pragma unroll
        for (int e = 0; e < NEXP; e++) { p[e] = expf(acc[e] - m); s += p[e]; }
        float inv = 1.f / s;
#pragma unroll
        for (int e = 0; e < NEXP; e++) p[e] *= inv;
        int i1 = 0;
#pragma unroll
        for (int e = 1; e < NEXP; e++) if (p[e] > p[i1]) i1 = e;  // strict >: lowest idx on tie
        int i2 = (i1 == 0) ? 1 : 0;
#pragma unroll
        for (int e = 0; e < NEXP; e++) if (e != i1 && p[e] > p[i2]) i2 = e;
        te[tok] = make_int2(i1, i2);
        tp[tok] = make_float2(p[i1], p[i2]);
    }
}

// ---- weight-pack tile b in [0,15360): 32x32 transpose fp32->bf16 ----------
__device__ __forceinline__ void ph_pack(int b, float* tf,
        const float* __restrict__ Wg_s, const float* __restrict__ Wu_s,
        const float* __restrict__ Wg_e, const float* __restrict__ Wu_e,
        const float* __restrict__ Wd_s, const float* __restrict__ Wd_e,
        bf16* __restrict__ Bg, bf16* __restrict__ Bu, bf16* __restrict__ Bd) {
    const float* src; bf16* dst; int C; long dstStride, dstBase; int tilesX;
    if (b < 1024)       { src = Wg_s; dst = Bg; C = 1024; dstStride = 1024; dstBase = 0; tilesX = 32; }
    else if (b < 2048)  { b -= 1024; src = Wu_s; dst = Bu; C = 1024; dstStride = 1024; dstBase = 0; tilesX = 32; }
    else if (b < 6144)  { b -= 2048; int z = b >> 9; b &= 511;
                          src = Wg_e + (long)z * DIM * DEXP; dst = Bg; C = 512;
                          dstStride = 1024; dstBase = (long)(DSH + z * DEXP) * 1024; tilesX = 16; }
    else if (b < 10240) { b -= 6144; int z = b >> 9; b &= 511;
                          src = Wu_e + (long)z * DIM * DEXP; dst = Bu; C = 512;
                          dstStride = 1024; dstBase = (long)(DSH + z * DEXP) * 1024; tilesX = 16; }
    else if (b < 11264) { b -= 10240; src = Wd_s; dst = Bd; C = 1024; dstStride = KH; dstBase = 0; tilesX = 32; }
    else                { b -= 11264; int z = b >> 9; b &= 511;
                          src = Wd_e + (long)z * DEXP * DIM; dst = Bd; C = 1024;
                          dstStride = KH; dstBase = DSH + (long)z * DEXP; tilesX = 32; }
    int tileX = b & (tilesX - 1), tileY = b / tilesX;
    int c0 = tileX * 32, tr0 = tileY * 32;
    {
        int row = threadIdx.x >> 3, ch = threadIdx.x & 7;
        float4 v = *(const float4*)(src + (long)(tr0 + row) * C + c0 + ch * 4);
        *(float4*)(&tf[row * 36 + ch * 4]) = v;
    }
    __syncthreads();
    {
        int dc = threadIdx.x & 31, ch = threadIdx.x >> 5;
        int j = ch * 4;
        B4 o{__float2bfloat16(tf[j * 36 + dc]),       __float2bfloat16(tf[(j + 1) * 36 + dc]),
             __float2bfloat16(tf[(j + 2) * 36 + dc]), __float2bfloat16(tf[(j + 3) * 36 + dc])};
        *(B4*)(dst + dstBase + (long)(c0 + dc) * dstStride + tr0 + j) = o;
    }
}

// ---- ballot-scan slot assignment for expert e (one wave); returns count ---
__device__ __forceinline__ int ph_assign(int e, int lane,
        const int2* __restrict__ te, const float2* __restrict__ tp,
        int* __restrict__ tok_list, float* __restrict__ cw,
        int* __restrict__ s1a, int* __restrict__ s2a) {
    int base = 0;
    for (int t0 = 0; t0 < NTOK; t0 += 64) {
        int t = t0 + lane;
        int2 ee = te[t];
        bool m1 = (ee.x == e), m2 = (ee.y == e);
        bool mt = m1 || m2;
        unsigned long long mask = __ballot(mt);
        int pre = __popcll(mask & ((1ull << lane) - 1ull));
        if (mt) {
            int slot = base + pre;
            tok_list[e * NTOK + slot] = t;
            float2 pp = tp[t];
            cw[e * NTOK + slot] = m1 ? pp.x : pp.y;
            if (m1) s1a[t] = slot; else s2a[t] = slot;
        }
        base += __popcll(mask);
    }
    int rc = (base + 127) & ~127;              // pad: (token 0, weight 0)
    for (int s = base + lane; s < rc; s += 64) {
        tok_list[e * NTOK + s] = 0;
        cw[e * NTOK + s] = 0.f;
    }
    return base;
}

// ---- gate+up SwiGLU GEMM tile b in [0,1280): 128x64, BK=32, swizzled LDS --
__device__ __forceinline__ void ph_gu(int b, bf16* sA, bf16* sB0, bf16* sB1,
        const bf16* __restrict__ X, const bf16* __restrict__ Bg, const bf16* __restrict__ Bu,
        const int* __restrict__ counts, const int* __restrict__ offs,
        const int* __restrict__ tok_list, const float* __restrict__ cw,
        bf16* __restrict__ Hs, bf16* __restrict__ He) {
    const bool routed = b < 1024;
    int e = 0, m, c;
    if (routed) {
        e = b >> 7; m = (b >> 3) & 15; c = b & 7;
        if (m * 128 >= counts[e]) return;
    } else {
        int bs = b - 1024; m = bs >> 4; c = bs & 15;
    }
    const int so = routed ? offs[e] : 0;
    const int colB0 = routed ? (DSH + e * DEXP + c * 64) : c * 64;
    const int tid = threadIdx.x;
    const int wave = tid >> 6, lane = tid & 63;
    const int wr = wave >> 1, wc = wave & 1;
    const int q = lane >> 4, l15 = lane & 15;
    const int koff = (q ^ ((l15 >> 1) & 3)) * 8;
    const int r0 = tid >> 2, c4 = tid & 3;
    const int r1 = r0 + 64;
    const int c4s = c4 ^ ((r0 >> 1) & 3);
    long aRow0, aRow1;
    if (routed) {
        const int* tl = tok_list + e * NTOK + m * 128;
        aRow0 = (long)tl[r0] * DIM;
        aRow1 = (long)tl[r1] * DIM;
    } else {
        aRow0 = (long)(m * 128 + r0) * DIM;
        aRow1 = (long)(m * 128 + r1) * DIM;
    }
    const long bRow = (long)(colB0 + r0) * DIM;

    floatx4 accG[4][2], accU[4][2];
    const floatx4 z4 = {0.f, 0.f, 0.f, 0.f};
#pragma unroll
    for (int i = 0; i < 4; i++)
#pragma unroll
        for (int j = 0; j < 2; j++) { accG[i][j] = z4; accU[i][j] = z4; }

    for (int k0 = 0; k0 < DIM; k0 += 32) {
        gl_lds16(X + aRow0 + k0 + c4s * 8, sA + (wave * 64) * 8);
        gl_lds16(X + aRow1 + k0 + c4s * 8, sA + (256 + wave * 64) * 8);
        gl_lds16(Bg + bRow + k0 + c4s * 8, sB0 + (wave * 64) * 8);
        gl_lds16(Bu + bRow + k0 + c4s * 8, sB1 + (wave * 64) * 8);
        __syncthreads();

        bf16x8 af[4], bg[2], bu[2];
#pragma unroll
        for (int rt = 0; rt < 4; rt++)
            af[rt] = *(const bf16x8*)(sA + (wr * 64 + rt * 16 + l15) * 32 + koff);
#pragma unroll
        for (int ct = 0; ct < 2; ct++) {
            int cb = (wc * 32 + ct * 16 + l15) * 32 + koff;
            bg[ct] = *(const bf16x8*)(sB0 + cb);
            bu[ct] = *(const bf16x8*)(sB1 + cb);
        }
#pragma unroll
        for (int rt = 0; rt < 4; rt++)
#pragma unroll
            for (int ct = 0; ct < 2; ct++) {
                accG[rt][ct] = __builtin_amdgcn_mfma_f32_16x16x32_bf16(af[rt], bg[ct], accG[rt][ct], 0, 0, 0);
                accU[rt][ct] = __builtin_amdgcn_mfma_f32_16x16x32_bf16(af[rt], bu[ct], accU[rt][ct], 0, 0, 0);
            }
        __syncthreads();
    }

    float wv[4][4];
#pragma unroll
    for (int rt = 0; rt < 4; rt++)
#pragma unroll
        for (int r = 0; r < 4; r++) {
            int srow = wr * 64 + rt * 16 + q * 4 + r;
            wv[rt][r] = routed ? cw[e * NTOK + m * 128 + srow] : 1.0f;
        }
#pragma unroll
    for (int rt = 0; rt < 4; rt++)
#pragma unroll
        for (int ct = 0; ct < 2; ct++)
#pragma unroll
            for (int r = 0; r < 4; r++) {
                int srow = wr * 64 + rt * 16 + q * 4 + r;
                int colLoc = c * 64 + wc * 32 + ct * 16 + l15;
                float g = accG[rt][ct][r];
                float u = accU[rt][ct][r];
                float h = (g / (1.f + __expf(-g))) * u * wv[rt][r];
                if (routed)
                    He[(long)(so + m * 128 + srow) * DEXP + colLoc] = __float2bfloat16(h);
                else
                    Hs[(long)(m * 128 + srow) * DSH + colLoc] = __float2bfloat16(h);
            }
}

// ---- down GEMM tile b in [0,2304): 128x64, BK=32, dense bf16 partials -----
__device__ __forceinline__ void ph_down(int b, bf16* sA, bf16* sB0,
        const bf16* __restrict__ Hs, const bf16* __restrict__ He,
        const bf16* __restrict__ Bd,
        const int* __restrict__ counts, const int* __restrict__ offs,
        bf16* __restrict__ Ys, bf16* __restrict__ Ye) {
    const bool routed = b < 2048;
    int e = 0, m, cc;
    if (routed) {
        e = b >> 8; m = (b >> 4) & 15; cc = b & 15;
        if (m * 128 >= counts[e]) return;
    } else {
        int bs = b - 2048; m = bs >> 4; cc = bs & 15;
    }
    const int so = routed ? offs[e] : 0;
    const bf16* A = routed ? He + (long)so * DEXP : Hs;
    bf16* Y = routed ? Ye + (long)so * DIM : Ys;
    const int astr = routed ? DEXP : DSH;
    const int ksteps = routed ? (DEXP / 32) : (DSH / 32);
    const int kg0 = routed ? (DSH + e * DEXP) : 0;
    const int tid = threadIdx.x;
    const int wave = tid >> 6, lane = tid & 63;
    const int wr = wave >> 1, wc = wave & 1;
    const int q = lane >> 4, l15 = lane & 15;
    const int koff = (q ^ ((l15 >> 1) & 3)) * 8;
    const int r0 = tid >> 2, c4 = tid & 3;
    const int r1 = r0 + 64;
    const int c4s = c4 ^ ((r0 >> 1) & 3);
    const long aRow0 = (long)(m * 128 + r0) * astr;
    const long aRow1 = (long)(m * 128 + r1) * astr;
    const long bRow = (long)(cc * 64 + r0) * KH + kg0;

    floatx4 acc[4][2];
    const floatx4 z4 = {0.f, 0.f, 0.f, 0.f};
#pragma unroll
    for (int i = 0; i < 4; i++)
#pragma unroll
        for (int j = 0; j < 2; j++) acc[i][j] = z4;

    for (int ks = 0; ks < ksteps; ks++) {
        const int k0 = ks * 32;
        gl_lds16(A + aRow0 + k0 + c4s * 8, sA + (wave * 64) * 8);
        gl_lds16(A + aRow1 + k0 + c4s * 8, sA + (256 + wave * 64) * 8);
        gl_lds16(Bd + bRow + k0 + c4s * 8, sB0 + (wave * 64) * 8);
        __syncthreads();

        bf16x8 af[4], bb[2];
#pragma unroll
        for (int rt = 0; rt < 4; rt++)
            af[rt] = *(const bf16x8*)(sA + (wr * 64 + rt * 16 + l15) * 32 + koff);
#pragma unroll
        for (int ct = 0; ct < 2; ct++)
            bb[ct] = *(const bf16x8*)(sB0 + (wc * 32 + ct * 16 + l15) * 32 + koff);
#pragma unroll
        for (int rt = 0; rt < 4; rt++)
#pragma unroll
            for (int ct = 0; ct < 2; ct++)
                acc[rt][ct] = __builtin_amdgcn_mfma_f32_16x16x32_bf16(af[rt], bb[ct], acc[rt][ct], 0, 0, 0);
        __syncthreads();
    }

#pragma unroll
    for (int rt = 0; rt < 4; rt++)
#pragma unroll
        for (int ct = 0; ct < 2; ct++)
#pragma unroll
            for (int r = 0; r < 4; r++) {
                int srow = wr * 64 + rt * 16 + q * 4 + r;
                int mc = cc * 64 + wc * 32 + ct * 16 + l15;
                Y[(long)(m * 128 + srow) * DIM + mc] = __float2bfloat16(acc[rt][ct][r]);
            }
}

// ---- combine element idx in [0, NTOK*DIM/8) -------------------------------
__device__ __forceinline__ void ph_combine(int idx,
        const bf16* __restrict__ Ys, const bf16* __restrict__ Ye,
        const int2* __restrict__ te, const int* __restrict__ s1a,
        const int* __restrict__ s2a, const int* __restrict__ offs,
        float* __restrict__ out) {
    int t = idx >> 7;
    int d = (idx & 127) * 8;
    int2 ee = te[t];
    long rr1 = (long)(offs[ee.x] + s1a[t]);
    long rr2 = (long)(offs[ee.y] + s2a[t]);
    bf16x8 a = *(const bf16x8*)(Ys + (long)t * DIM + d);
    bf16x8 p = *(const bf16x8*)(Ye + rr1 * DIM + d);
    bf16x8 r = *(const bf16x8*)(Ye + rr2 * DIM + d);
    float* o = out + (long)t * DIM + d;
#pragma unroll
    for (int i = 0; i < 8; i++)
        o[i] = b2f(a[i]) + b2f(p[i]) + b2f(r[i]);
}

// ===========================================================================
// Persistent cooperative kernel (primary path). Grid sized by occupancy query.
// ===========================================================================
__global__ __launch_bounds__(256, 3) void moe_coop(
        const float* __restrict__ x, const float* __restrict__ Wg,
        const float* __restrict__ Wg_s, const float* __restrict__ Wu_s,
        const float* __restrict__ Wg_e, const float* __restrict__ Wu_e,
        const float* __restrict__ Wd_s, const float* __restrict__ Wd_e,
        bf16* __restrict__ Xb, int2* __restrict__ te, float2* __restrict__ tp,
        bf16* __restrict__ Bg, bf16* __restrict__ Bu, bf16* __restrict__ Bd,
        int* __restrict__ counts, int* __restrict__ offs,
        int* __restrict__ tok_list, float* __restrict__ cw,
        int* __restrict__ s1a, int* __restrict__ s2a,
        bf16* __restrict__ Hs, bf16* __restrict__ He,
        bf16* __restrict__ Ys, bf16* __restrict__ Ye,
        float* __restrict__ out) {
    cg::grid_group grid = cg::this_grid();
    __shared__ __align__(16) bf16 smem[8192];   // 16 KB
    __shared__ int scnt[NEXP];
    bf16* sA = smem;
    bf16* sB0 = smem + 4096;
    bf16* sB1 = smem + 6144;

    // P0: gating + pack
    for (int wb = blockIdx.x; wb < 512 + 15360; wb += gridDim.x) {
        if (wb < 512) ph_gate(wb, x, Wg, Xb, te, tp);
        else ph_pack(wb - 512, (float*)smem, Wg_s, Wu_s, Wg_e, Wu_e, Wd_s, Wd_e, Bg, Bu, Bd);
        __syncthreads();
    }
    grid.sync();

    // P1: assignment (block 0; 4 waves x 2 experts)
    if (blockIdx.x == 0) {
        const int wave = threadIdx.x >> 6, lane = threadIdx.x & 63;
#pragma unroll
        for (int eo = 0; eo < 2; eo++) {
            int e = wave * 2 + eo;
            int cnt = ph_assign(e, lane, te, tp, tok_list, cw, s1a, s2a);
            if (lane == 0) scnt[e] = cnt;
        }
        __syncthreads();
        if (threadIdx.x == 0) {
            int o = 0;
#pragma unroll
            for (int i = 0; i < NEXP; i++) {
                counts[i] = scnt[i];
                offs[i] = o;
                o += (scnt[i] + 127) & ~127;
            }
        }
    }
    grid.sync();

    // P2: gate+up GEMM
    for (int b = blockIdx.x; b < 1280; b += gridDim.x)
        ph_gu(b, sA, sB0, sB1, Xb, Bg, Bu, counts, offs, tok_list, cw, Hs, He);
    grid.sync();

    // P3: down GEMM
    for (int b = blockIdx.x; b < 2304; b += gridDim.x)
        ph_down(b, sA, sB0, Hs, He, Bd, counts, offs, Ys, Ye);
    grid.sync();

    // P4: combine
    for (int idx = blockIdx.x * 256 + threadIdx.x; idx < NTOK * DIM / 8;
         idx += gridDim.x * 256)
        ph_combine(idx, Ys, Ye, te, s1a, s2a, offs, out);
}

// ===========================================================================
// Fallback kernels (round-5 structure, known-good 208 µs path)
// ===========================================================================
__global__ __launch_bounds__(256) void prep_kernel(
        const float* x, const float* Wg,
        const float* Wg_s, const float* Wu_s, const float* Wg_e, const float* Wu_e,
        const float* Wd_s, const float* Wd_e,
        bf16* Xb, int2* te, float2* tp, bf16* Bg, bf16* Bu, bf16* Bd) {
    __shared__ __align__(16) float tf[32 * 36];
    if (blockIdx.x < 512) ph_gate(blockIdx.x, x, Wg, Xb, te, tp);
    else ph_pack(blockIdx.x - 512, tf, Wg_s, Wu_s, Wg_e, Wu_e, Wd_s, Wd_e, Bg, Bu, Bd);
}

__global__ __launch_bounds__(512) void assign_kernel(
        const int2* te, const float2* tp, int* counts, int* offs,
        int* tok_list, float* cw, int* s1a, int* s2a) {
    __shared__ int scnt[NEXP];
    const int e = threadIdx.x >> 6, lane = threadIdx.x & 63;
    int cnt = ph_assign(e, lane, te, tp, tok_list, cw, s1a, s2a);
    if (lane == 0) scnt[e] = cnt;
    __syncthreads();
    if (threadIdx.x == 0) {
        int o = 0;
#pragma unroll
        for (int i = 0; i < NEXP; i++) {
            counts[i] = scnt[i];
            offs[i] = o;
            o += (scnt[i] + 127) & ~127;
        }
    }
}

__global__ __launch_bounds__(256) void gu_kernel(
        const bf16* X, const bf16* Bg, const bf16* Bu,
        const int* counts, const int* offs, const int* tok_list, const float* cw,
        bf16* Hs, bf16* He) {
    __shared__ __align__(16) bf16 smem[8192];
    ph_gu(blockIdx.x, smem, smem + 4096, smem + 6144, X, Bg, Bu,
          counts, offs, tok_list, cw, Hs, He);
}

__global__ __launch_bounds__(256) void down_kernel(
        const bf16* Hs, const bf16* He, const bf16* Bd,
        const int* counts, const int* offs, bf16* Ys, bf16* Ye) {
    __shared__ __align__(16) bf16 smem[6144];
    ph_down(blockIdx.x, smem, smem + 4096, Hs, He, Bd, counts, offs, Ys, Ye);
}

__global__ __launch_bounds__(256) void combine_kernel(
        const bf16* Ys, const bf16* Ye, const int2* te,
        const int* s1a, const int* s2a, const int* offs, float* out) {
    ph_combine(blockIdx.x * 256 + threadIdx.x, Ys, Ye, te, s1a, s2a, offs, out);
}

// ---------------------------------------------------------------------------
extern "C" void kernel_launch(void* const* d_in, const int* in_sizes, int n_in,
                              void* d_out, int out_size, void* d_ws, size_t ws_size,
                              hipStream_t stream) {
    const float* x    = (const float*)d_in[0];
    const float* W_g  = (const float*)d_in[1];
    const float* Wg_e = (const float*)d_in[2];
    const float* Wu_e = (const float*)d_in[3];
    const float* Wd_e = (const float*)d_in[4];
    const float* Wg_s = (const float*)d_in[5];
    const float* Wu_s = (const float*)d_in[6];
    const float* Wd_s = (const float*)d_in[7];
    float* out = (float*)d_out;

    bf16* Xb = (bf16*)d_ws;                            // [2048,1024]
    bf16* Bg = Xb + (size_t)NTOK * DIM;                // [5120,1024]
    bf16* Bu = Bg + (size_t)KH * DIM;                  // [5120,1024]
    bf16* Bd = Bu + (size_t)KH * DIM;                  // [1024,5120]
    bf16* Hs = Bd + (size_t)DIM * KH;                  // [2048,1024]
    bf16* He = Hs + (size_t)NTOK * DSH;                // [5120,512] compacted
    bf16* Ys = He + (size_t)MAXROWS * DEXP;            // [2048,1024]
    bf16* Ye = Ys + (size_t)NTOK * DIM;                // [5120,1024] compacted
    int*  counts   = (int*)(Ye + (size_t)MAXROWS * DIM);
    int*  offs     = counts + NEXP;
    int*  tok_list = offs + NEXP;                      // [8,2048]
    float* cw      = (float*)(tok_list + NEXP * NTOK); // [8,2048]
    int*  s1a      = (int*)(cw + NEXP * NTOK);         // [2048]
    int*  s2a      = s1a + NTOK;                       // [2048]
    int2* te       = (int2*)(s2a + NTOK);              // [2048]
    float2* tp     = (float2*)(te + NTOK);             // [2048]

    // ---- primary: cooperative persistent kernel, occupancy-sized grid ----
    bool coop_ok = false;
    int maxB = 0;
    hipError_t qerr = hipOccupancyMaxActiveBlocksPerMultiprocessor(&maxB, moe_coop, 256, 0);
    if (qerr == hipSuccess && maxB > 0) {
        int grid = maxB * 256;                 // 256 CUs on MI355X
        if (grid > 1024) grid = 1024;
        void* args[] = {
            (void*)&x, (void*)&W_g, (void*)&Wg_s, (void*)&Wu_s, (void*)&Wg_e, (void*)&Wu_e,
            (void*)&Wd_s, (void*)&Wd_e, (void*)&Xb, (void*)&te, (void*)&tp,
            (void*)&Bg, (void*)&Bu, (void*)&Bd, (void*)&counts, (void*)&offs,
            (void*)&tok_list, (void*)&cw, (void*)&s1a, (void*)&s2a,
            (void*)&Hs, (void*)&He, (void*)&Ys, (void*)&Ye, (void*)&out
        };
        hipError_t lerr = hipLaunchCooperativeKernel((void*)moe_coop, dim3(grid),
                                                     dim3(256), args, 0, stream);
        coop_ok = (lerr == hipSuccess);
    }

    // ---- fallback: known-good 5-launch path ----
    if (!coop_ok) {
        prep_kernel<<<512 + 15360, 256, 0, stream>>>(x, W_g, Wg_s, Wu_s, Wg_e, Wu_e,
                                                     Wd_s, Wd_e, Xb, te, tp, Bg, Bu, Bd);
        assign_kernel<<<1, 512, 0, stream>>>(te, tp, counts, offs, tok_list, cw, s1a, s2a);
        gu_kernel<<<1280, 256, 0, stream>>>(Xb, Bg, Bu, counts, offs, tok_list, cw, Hs, He);
        down_kernel<<<2304, 256, 0, stream>>>(Hs, He, Bd, counts, offs, Ys, Ye);
        combine_kernel<<<NTOK * DIM / 8 / 256, 256, 0, stream>>>(Ys, Ye, te, s1a, s2a, offs, out);
    }
}

// Round 9
// 212.094 us; speedup vs baseline: 2.3410x; 2.3410x over previous
//
#include <hip/hip_runtime.h>
#include <hip/hip_bf16.h>

#define NTOK 2048
#define DIM  1024
#define DEXP 512
#define NEXP 8
#define DSH  1024          // shared expert width
#define KH   5120          // DSH + NEXP*DEXP
#define MAXROWS 5120       // compacted routed slots upper bound

typedef __hip_bfloat16 bf16;
typedef __attribute__((ext_vector_type(8))) short bf16x8;
typedef __attribute__((ext_vector_type(4))) float floatx4;

// async global->LDS, 16B/lane. LDS dest = wave-uniform base + lane*16 (HW adds).
__device__ __forceinline__ void gl_lds16(const bf16* g, bf16* l) {
    __builtin_amdgcn_global_load_lds(
        (const __attribute__((address_space(1))) void*)g,
        (__attribute__((address_space(3))) void*)l, 16, 0, 0);
}

__device__ __forceinline__ float b2f(short s) {
    union { float f; unsigned u; } v;
    v.u = ((unsigned)(unsigned short)s) << 16;
    return v.f;
}

struct B4 { bf16 a, b, c, d; };   // 8-byte bf16 quad

// ---------------------------------------------------------------------------
// prep: fused gating (+x->bf16 cast) and weight packing, one dispatch.
//   blocks 0..511     : gating, 4 tokens/block (one wave/token)
//   blocks 512..16383 : 32x32 transpose-cast tiles into Bg/Bu/Bd
// ---------------------------------------------------------------------------
__global__ __launch_bounds__(256) void prep_kernel(
        const float* __restrict__ x, const float* __restrict__ Wg,
        const float* __restrict__ Wg_s, const float* __restrict__ Wu_s,
        const float* __restrict__ Wg_e, const float* __restrict__ Wu_e,
        const float* __restrict__ Wd_s, const float* __restrict__ Wd_e,
        bf16* __restrict__ Xb, int2* __restrict__ te, float2* __restrict__ tp,
        bf16* __restrict__ Bg, bf16* __restrict__ Bu, bf16* __restrict__ Bd) {
    __shared__ float t[32][36];
    if (blockIdx.x < 512) {
        // ---- gating + cast ----
        int tok = blockIdx.x * 4 + (threadIdx.x >> 6);
        int lane = threadIdx.x & 63;
        const float* xr = x + (long)tok * DIM;
        bf16* xo = Xb + (long)tok * DIM;
        float acc[NEXP] = {0.f, 0.f, 0.f, 0.f, 0.f, 0.f, 0.f, 0.f};
#pragma unroll
        for (int i = 0; i < 4; i++) {
            int d = lane * 4 + i * 256;
            float4 xv = *(const float4*)(xr + d);
            B4 o{__float2bfloat16(xv.x), __float2bfloat16(xv.y),
                 __float2bfloat16(xv.z), __float2bfloat16(xv.w)};
            *(B4*)(xo + d) = o;
#pragma unroll
            for (int j = 0; j < 4; j++) {
                float xs = (j == 0) ? xv.x : (j == 1) ? xv.y : (j == 2) ? xv.z : xv.w;
                float4 w0 = *(const float4*)(Wg + (d + j) * NEXP);
                float4 w1 = *(const float4*)(Wg + (d + j) * NEXP + 4);
                acc[0] += xs * w0.x; acc[1] += xs * w0.y; acc[2] += xs * w0.z; acc[3] += xs * w0.w;
                acc[4] += xs * w1.x; acc[5] += xs * w1.y; acc[6] += xs * w1.z; acc[7] += xs * w1.w;
            }
        }
#pragma unroll
        for (int e = 0; e < NEXP; e++)
#pragma unroll
            for (int off = 32; off; off >>= 1)
                acc[e] += __shfl_xor(acc[e], off);
        if (lane == 0) {
            float m = acc[0];
#pragma unroll
            for (int e = 1; e < NEXP; e++) m = fmaxf(m, acc[e]);
            float p[NEXP], s = 0.f;
#pragma unroll
            for (int e = 0; e < NEXP; e++) { p[e] = expf(acc[e] - m); s += p[e]; }
            float inv = 1.f / s;
#pragma unroll
            for (int e = 0; e < NEXP; e++) p[e] *= inv;
            int i1 = 0;
#pragma unroll
            for (int e = 1; e < NEXP; e++) if (p[e] > p[i1]) i1 = e;  // strict >: lowest idx on tie
            int i2 = (i1 == 0) ? 1 : 0;
#pragma unroll
            for (int e = 0; e < NEXP; e++) if (e != i1 && p[e] > p[i2]) i2 = e;
            te[tok] = make_int2(i1, i2);
            tp[tok] = make_float2(p[i1], p[i2]);
        }
        return;
    }
    // ---- weight packing ----
    int b = blockIdx.x - 512;
    const float* src; bf16* dst; int C; long dstStride, dstBase; int tilesX;
    if (b < 1024)       { src = Wg_s; dst = Bg; C = 1024; dstStride = 1024; dstBase = 0; tilesX = 32; }
    else if (b < 2048)  { b -= 1024; src = Wu_s; dst = Bu; C = 1024; dstStride = 1024; dstBase = 0; tilesX = 32; }
    else if (b < 6144)  { b -= 2048; int z = b >> 9; b &= 511;
                          src = Wg_e + (long)z * DIM * DEXP; dst = Bg; C = 512;
                          dstStride = 1024; dstBase = (long)(DSH + z * DEXP) * 1024; tilesX = 16; }
    else if (b < 10240) { b -= 6144; int z = b >> 9; b &= 511;
                          src = Wu_e + (long)z * DIM * DEXP; dst = Bu; C = 512;
                          dstStride = 1024; dstBase = (long)(DSH + z * DEXP) * 1024; tilesX = 16; }
    else if (b < 11264) { b -= 10240; src = Wd_s; dst = Bd; C = 1024; dstStride = KH; dstBase = 0; tilesX = 32; }
    else                { b -= 11264; int z = b >> 9; b &= 511;
                          src = Wd_e + (long)z * DEXP * DIM; dst = Bd; C = 1024;
                          dstStride = KH; dstBase = DSH + (long)z * DEXP; tilesX = 32; }
    int tileX = b & (tilesX - 1), tileY = b / tilesX;
    int c0 = tileX * 32, tr0 = tileY * 32;
    {
        int row = threadIdx.x >> 3, ch = threadIdx.x & 7;
        float4 v = *(const float4*)(src + (long)(tr0 + row) * C + c0 + ch * 4);
        *(float4*)(&t[row][ch * 4]) = v;
    }
    __syncthreads();
    {
        int dc = threadIdx.x & 31, ch = threadIdx.x >> 5;
        int j = ch * 4;
        B4 o{__float2bfloat16(t[j][dc]), __float2bfloat16(t[j + 1][dc]),
             __float2bfloat16(t[j + 2][dc]), __float2bfloat16(t[j + 3][dc])};
        *(B4*)(dst + dstBase + (long)(c0 + dc) * dstStride + tr0 + j) = o;
    }
}

// ---------------------------------------------------------------------------
// Slot assignment: 1 block, 8 waves; wave e ballot-scans all tokens ->
// deterministic slots; writes its own pad slots (tok 0, cw 0). Zero atomics.
// ---------------------------------------------------------------------------
__global__ __launch_bounds__(512) void assign_kernel(const int2* __restrict__ te,
                                                     const float2* __restrict__ tp,
                                                     int* __restrict__ counts,
                                                     int* __restrict__ offs,
                                                     int* __restrict__ tok_list,
                                                     float* __restrict__ cw,
                                                     int* __restrict__ s1a,
                                                     int* __restrict__ s2a) {
    __shared__ int cnt[NEXP];
    const int e = threadIdx.x >> 6;
    const int lane = threadIdx.x & 63;
    int base = 0;
    for (int t0 = 0; t0 < NTOK; t0 += 64) {
        int t = t0 + lane;
        int2 ee = te[t];
        bool m1 = (ee.x == e), m2 = (ee.y == e);
        bool mt = m1 || m2;
        unsigned long long mask = __ballot(mt);
        int pre = __popcll(mask & ((1ull << lane) - 1ull));
        if (mt) {
            int slot = base + pre;
            tok_list[e * NTOK + slot] = t;
            float2 pp = tp[t];
            cw[e * NTOK + slot] = m1 ? pp.x : pp.y;
            if (m1) s1a[t] = slot; else s2a[t] = slot;
        }
        base += __popcll(mask);
    }
    int rc = (base + 127) & ~127;              // pad: (token 0, weight 0)
    for (int s = base + lane; s < rc; s += 64) {
        tok_list[e * NTOK + s] = 0;
        cw[e * NTOK + s] = 0.f;
    }
    if (lane == 0) cnt[e] = base;
    __syncthreads();
    if (threadIdx.x == 0) {
        int o = 0;
#pragma unroll
        for (int i = 0; i < NEXP; i++) {
            counts[i] = cnt[i];
            offs[i] = o;
            o += (cnt[i] + 127) & ~127;
        }
    }
}

// ---------------------------------------------------------------------------
// gate+up SwiGLU GEMM (shared + gathered routed), tile 128x64, BK=32,
// 4 waves 2x2 (wave 64x32 for BOTH G and U). XOR-swizzled LDS -> 0 conflicts.
// Routed output rows COMPACTED: He row = offs[e] + m*128 + srow.
// ---------------------------------------------------------------------------
__global__ __launch_bounds__(256) void gu_kernel(const bf16* __restrict__ X,
                                                 const bf16* __restrict__ Bg,
                                                 const bf16* __restrict__ Bu,
                                                 const int* __restrict__ counts,
                                                 const int* __restrict__ offs,
                                                 const int* __restrict__ tok_list,
                                                 const float* __restrict__ cw,
                                                 bf16* __restrict__ Hs,
                                                 bf16* __restrict__ He) {
    __shared__ __align__(16) bf16 sA[128 * 32];
    __shared__ __align__(16) bf16 sBg[64 * 32];
    __shared__ __align__(16) bf16 sBu[64 * 32];

    const int b = blockIdx.x;
    const bool routed = b < 1024;
    int e = 0, m, c;
    if (routed) {
        e = b >> 7; m = (b >> 3) & 15; c = b & 7;
        if (m * 128 >= counts[e]) return;
    } else {
        int bs = b - 1024; m = bs >> 4; c = bs & 15;
    }
    const int so = routed ? offs[e] : 0;
    const int colB0 = routed ? (DSH + e * DEXP + c * 64) : c * 64;

    const int tid = threadIdx.x;
    const int wave = tid >> 6, lane = tid & 63;
    const int wr = wave >> 1, wc = wave & 1;
    const int q = lane >> 4, l15 = lane & 15;
    const int koff = (q ^ ((l15 >> 1) & 3)) * 8;
    const int r0 = tid >> 2, c4 = tid & 3;
    const int r1 = r0 + 64;
    const int c4s = c4 ^ ((r0 >> 1) & 3);
    long aRow0, aRow1;
    if (routed) {
        const int* tl = tok_list + e * NTOK + m * 128;
        aRow0 = (long)tl[r0] * DIM;
        aRow1 = (long)tl[r1] * DIM;
    } else {
        aRow0 = (long)(m * 128 + r0) * DIM;
        aRow1 = (long)(m * 128 + r1) * DIM;
    }
    const long bRow = (long)(colB0 + r0) * DIM;

    floatx4 accG[4][2], accU[4][2];
    const floatx4 z4 = {0.f, 0.f, 0.f, 0.f};
#pragma unroll
    for (int i = 0; i < 4; i++)
#pragma unroll
        for (int j = 0; j < 2; j++) { accG[i][j] = z4; accU[i][j] = z4; }

    for (int k0 = 0; k0 < DIM; k0 += 32) {
        gl_lds16(X + aRow0 + k0 + c4s * 8, sA + (wave * 64) * 8);
        gl_lds16(X + aRow1 + k0 + c4s * 8, sA + (256 + wave * 64) * 8);
        gl_lds16(Bg + bRow + k0 + c4s * 8, sBg + (wave * 64) * 8);
        gl_lds16(Bu + bRow + k0 + c4s * 8, sBu + (wave * 64) * 8);
        __syncthreads();

        bf16x8 af[4], bg[2], bu[2];
#pragma unroll
        for (int rt = 0; rt < 4; rt++)
            af[rt] = *(const bf16x8*)(sA + (wr * 64 + rt * 16 + l15) * 32 + koff);
#pragma unroll
        for (int ct = 0; ct < 2; ct++) {
            int cb = (wc * 32 + ct * 16 + l15) * 32 + koff;
            bg[ct] = *(const bf16x8*)(sBg + cb);
            bu[ct] = *(const bf16x8*)(sBu + cb);
        }
#pragma unroll
        for (int rt = 0; rt < 4; rt++)
#pragma unroll
            for (int ct = 0; ct < 2; ct++) {
                accG[rt][ct] = __builtin_amdgcn_mfma_f32_16x16x32_bf16(af[rt], bg[ct], accG[rt][ct], 0, 0, 0);
                accU[rt][ct] = __builtin_amdgcn_mfma_f32_16x16x32_bf16(af[rt], bu[ct], accU[rt][ct], 0, 0, 0);
            }
        __syncthreads();
    }

    float wv[4][4];
#pragma unroll
    for (int rt = 0; rt < 4; rt++)
#pragma unroll
        for (int r = 0; r < 4; r++) {
            int srow = wr * 64 + rt * 16 + q * 4 + r;
            wv[rt][r] = routed ? cw[e * NTOK + m * 128 + srow] : 1.0f;
        }
#pragma unroll
    for (int rt = 0; rt < 4; rt++)
#pragma unroll
        for (int ct = 0; ct < 2; ct++)
#pragma unroll
            for (int r = 0; r < 4; r++) {
                int srow = wr * 64 + rt * 16 + q * 4 + r;
                int colLoc = c * 64 + wc * 32 + ct * 16 + l15;
                float g = accG[rt][ct][r];
                float u = accU[rt][ct][r];
                float h = (g / (1.f + __expf(-g))) * u * wv[rt][r];
                if (routed)
                    He[(long)(so + m * 128 + srow) * DEXP + colLoc] = __float2bfloat16(h);
                else
                    Hs[(long)(m * 128 + srow) * DSH + colLoc] = __float2bfloat16(h);
            }
}

// ---------------------------------------------------------------------------
// down GEMM, 128x128 tile (m97 ratio: 16 MFMA : 8 ds_read : 4 gl_lds per
// k-step), BK=32, 4 waves 2x2 each 64x64, acc 4x4, swizzled LDS, no atomics.
//   routed (b<1024): e=b>>7, m=(b>>4)&... -> Ye[slotRow][1024]
//   shared (b>=1024): Ys[token][1024]
// ---------------------------------------------------------------------------
__global__ __launch_bounds__(256) void down_kernel(const bf16* __restrict__ Hs,
                                                   const bf16* __restrict__ He,
                                                   const bf16* __restrict__ Bd,
                                                   const int* __restrict__ counts,
                                                   const int* __restrict__ offs,
                                                   bf16* __restrict__ Ys,
                                                   bf16* __restrict__ Ye) {
    __shared__ __align__(16) bf16 sA[128 * 32];   // 8 KB
    __shared__ __align__(16) bf16 sB[128 * 32];   // 8 KB

    const int b = blockIdx.x;
    const bool routed = b < 1024;
    int e = 0, m, cc;
    if (routed) {
        e = b >> 7; int rem = b & 127; m = rem >> 3; cc = rem & 7;
        if (m * 128 >= counts[e]) return;
    } else {
        int bs = b - 1024; m = bs >> 3; cc = bs & 7;
    }
    const int so = routed ? offs[e] : 0;
    const bf16* A = routed ? He + (long)so * DEXP : Hs;
    bf16* Y = routed ? Ye + (long)so * DIM : Ys;
    const int astr = routed ? DEXP : DSH;
    const int ksteps = routed ? (DEXP / 32) : (DSH / 32);
    const int kg0 = routed ? (DSH + e * DEXP) : 0;

    const int tid = threadIdx.x;
    const int wave = tid >> 6, lane = tid & 63;
    const int wr = wave >> 1, wc = wave & 1;
    const int q = lane >> 4, l15 = lane & 15;
    const int koff = (q ^ ((l15 >> 1) & 3)) * 8;
    const int r0 = tid >> 2, c4 = tid & 3;
    const int r1 = r0 + 64;
    const int c4s = c4 ^ ((r0 >> 1) & 3);          // same for r1 (r1>>1 diff = 32)
    const long aRow0 = (long)(m * 128 + r0) * astr;
    const long aRow1 = (long)(m * 128 + r1) * astr;
    const long bRow0 = (long)(cc * 128 + r0) * KH + kg0;
    const long bRow1 = (long)(cc * 128 + r1) * KH + kg0;

    floatx4 acc[4][4];
    const floatx4 z4 = {0.f, 0.f, 0.f, 0.f};
#pragma unroll
    for (int i = 0; i < 4; i++)
#pragma unroll
        for (int j = 0; j < 4; j++) acc[i][j] = z4;

    for (int ks = 0; ks < ksteps; ks++) {
        const int k0 = ks * 32;
        gl_lds16(A + aRow0 + k0 + c4s * 8, sA + (wave * 64) * 8);
        gl_lds16(A + aRow1 + k0 + c4s * 8, sA + (256 + wave * 64) * 8);
        gl_lds16(Bd + bRow0 + k0 + c4s * 8, sB + (wave * 64) * 8);
        gl_lds16(Bd + bRow1 + k0 + c4s * 8, sB + (256 + wave * 64) * 8);
        __syncthreads();

        bf16x8 af[4], bb[4];
#pragma unroll
        for (int rt = 0; rt < 4; rt++)
            af[rt] = *(const bf16x8*)(sA + (wr * 64 + rt * 16 + l15) * 32 + koff);
#pragma unroll
        for (int ct = 0; ct < 4; ct++)
            bb[ct] = *(const bf16x8*)(sB + (wc * 64 + ct * 16 + l15) * 32 + koff);
#pragma unroll
        for (int rt = 0; rt < 4; rt++)
#pragma unroll
            for (int ct = 0; ct < 4; ct++)
                acc[rt][ct] = __builtin_amdgcn_mfma_f32_16x16x32_bf16(af[rt], bb[ct], acc[rt][ct], 0, 0, 0);
        __syncthreads();
    }

#pragma unroll
    for (int rt = 0; rt < 4; rt++)
#pragma unroll
        for (int ct = 0; ct < 4; ct++)
#pragma unroll
            for (int r = 0; r < 4; r++) {
                int srow = wr * 64 + rt * 16 + q * 4 + r;
                int mc = cc * 128 + wc * 64 + ct * 16 + l15;
                Y[(long)(m * 128 + srow) * DIM + mc] = __float2bfloat16(acc[rt][ct][r]);
            }
}

// ---------------------------------------------------------------------------
// Final gather-combine: out[t] = Ys[t] + Ye[offs[e1]+s1] + Ye[offs[e2]+s2].
// ---------------------------------------------------------------------------
__global__ __launch_bounds__(256) void combine_kernel(const bf16* __restrict__ Ys,
                                                      const bf16* __restrict__ Ye,
                                                      const int2* __restrict__ te,
                                                      const int* __restrict__ s1a,
                                                      const int* __restrict__ s2a,
                                                      const int* __restrict__ offs,
                                                      float* __restrict__ out) {
    int idx = blockIdx.x * 256 + threadIdx.x;   // NTOK*DIM/8 total
    int t = idx >> 7;
    int d = (idx & 127) * 8;
    int2 ee = te[t];
    long rr1 = (long)(offs[ee.x] + s1a[t]);
    long rr2 = (long)(offs[ee.y] + s2a[t]);
    bf16x8 a = *(const bf16x8*)(Ys + (long)t * DIM + d);
    bf16x8 p = *(const bf16x8*)(Ye + rr1 * DIM + d);
    bf16x8 r = *(const bf16x8*)(Ye + rr2 * DIM + d);
    float* o = out + (long)t * DIM + d;
#pragma unroll
    for (int i = 0; i < 8; i++)
        o[i] = b2f(a[i]) + b2f(p[i]) + b2f(r[i]);
}

// ---------------------------------------------------------------------------
extern "C" void kernel_launch(void* const* d_in, const int* in_sizes, int n_in,
                              void* d_out, int out_size, void* d_ws, size_t ws_size,
                              hipStream_t stream) {
    const float* x    = (const float*)d_in[0];
    const float* W_g  = (const float*)d_in[1];
    const float* Wg_e = (const float*)d_in[2];
    const float* Wu_e = (const float*)d_in[3];
    const float* Wd_e = (const float*)d_in[4];
    const float* Wg_s = (const float*)d_in[5];
    const float* Wu_s = (const float*)d_in[6];
    const float* Wd_s = (const float*)d_in[7];
    float* out = (float*)d_out;

    bf16* Xb = (bf16*)d_ws;                            // [2048,1024]
    bf16* Bg = Xb + (size_t)NTOK * DIM;                // [5120,1024]
    bf16* Bu = Bg + (size_t)KH * DIM;                  // [5120,1024]
    bf16* Bd = Bu + (size_t)KH * DIM;                  // [1024,5120]
    bf16* Hs = Bd + (size_t)DIM * KH;                  // [2048,1024]
    bf16* He = Hs + (size_t)NTOK * DSH;                // [5120,512] compacted
    bf16* Ys = He + (size_t)MAXROWS * DEXP;            // [2048,1024]
    bf16* Ye = Ys + (size_t)NTOK * DIM;                // [5120,1024] compacted
    int*  counts   = (int*)(Ye + (size_t)MAXROWS * DIM);
    int*  offs     = counts + NEXP;
    int*  tok_list = offs + NEXP;                      // [8,2048]
    float* cw      = (float*)(tok_list + NEXP * NTOK); // [8,2048]
    int*  s1a      = (int*)(cw + NEXP * NTOK);         // [2048]
    int*  s2a      = s1a + NTOK;                       // [2048]
    int2* te       = (int2*)(s2a + NTOK);              // [2048]
    float2* tp     = (float2*)(te + NTOK);             // [2048]

    prep_kernel<<<512 + 15360, 256, 0, stream>>>(x, W_g, Wg_s, Wu_s, Wg_e, Wu_e,
                                                 Wd_s, Wd_e, Xb, te, tp, Bg, Bu, Bd);
    assign_kernel<<<1, 512, 0, stream>>>(te, tp, counts, offs, tok_list, cw, s1a, s2a);
    gu_kernel<<<1280, 256, 0, stream>>>(Xb, Bg, Bu, counts, offs, tok_list, cw, Hs, He);
    down_kernel<<<1152, 256, 0, stream>>>(Hs, He, Bd, counts, offs, Ys, Ye);
    combine_kernel<<<NTOK * DIM / 8 / 256, 256, 0, stream>>>(Ys, Ye, te, s1a, s2a, offs, out);
}